// Round 1
// baseline (791.159 us; speedup 1.0000x reference)
//
#include <hip/hip_runtime.h>

#define M_DIM 16384
#define N_DIM 4096
#define K_DIM 4096
#define NCLUST 16

#define BM 128
#define BN 128
#define BK 32

typedef unsigned short u16;
typedef float floatx4 __attribute__((ext_vector_type(4)));
typedef short short8 __attribute__((ext_vector_type(8)));

typedef const unsigned int __attribute__((address_space(1))) gu32;
typedef unsigned int __attribute__((address_space(3))) lu32;

__device__ __forceinline__ u16 f2bf(float f) {
  union { float f; unsigned u; } a; a.f = f;
  unsigned u = a.u;
  unsigned r = (u + 0x7FFFu + ((u >> 16) & 1u)) >> 16;
  return (u16)r;
}

// ---------------- zero scratch accumulators ----------------
__global__ __launch_bounds__(256) void zero_kernel(float* __restrict__ p, int n) {
  int i = blockIdx.x * 256 + threadIdx.x;
  if (i < n) p[i] = 0.f;
}

// ---------------- z row-normalize -> bf16, plus copy z -> out1 ----------------
__global__ __launch_bounds__(256) void znorm_copy_kernel(const float* __restrict__ z,
                                                         float* __restrict__ out1,
                                                         u16* __restrict__ zn) {
  const int row = blockIdx.x;
  const int t = threadIdx.x;
  const size_t base = (size_t)row * K_DIM;
  const float4* zr = (const float4*)(z + base);
  float4 v[4];
  float ss = 0.f;
#pragma unroll
  for (int i = 0; i < 4; i++) {
    v[i] = zr[t + i * 256];
    ss += v[i].x * v[i].x + v[i].y * v[i].y + v[i].z * v[i].z + v[i].w * v[i].w;
  }
#pragma unroll
  for (int m = 1; m <= 32; m <<= 1) ss += __shfl_xor(ss, m, 64);
  __shared__ float red[4];
  if ((t & 63) == 0) red[t >> 6] = ss;
  __syncthreads();
  float tot = red[0] + red[1] + red[2] + red[3];
  float rn = 1.0f / fmaxf(sqrtf(tot), 1e-8f);
  float4* o1 = (float4*)(out1 + base);
  uint2* znr = (uint2*)(zn + base);
#pragma unroll
  for (int i = 0; i < 4; i++) {
    o1[t + i * 256] = v[i];
    uint2 p;
    p.x = (unsigned)f2bf(v[i].x * rn) | ((unsigned)f2bf(v[i].y * rn) << 16);
    p.y = (unsigned)f2bf(v[i].z * rn) | ((unsigned)f2bf(v[i].w * rn) << 16);
    znr[t + i * 256] = p;
  }
}

// ---------------- D column squared-norms ----------------
__global__ __launch_bounds__(256) void colsq_kernel(const float* __restrict__ D,
                                                    float* __restrict__ colsq) {
  const int col = blockIdx.x * 256 + threadIdx.x;
  const int r0 = blockIdx.y * 128;
  float ss = 0.f;
#pragma unroll 4
  for (int r = 0; r < 128; r++) {
    float d = D[(size_t)(r0 + r) * N_DIM + col];
    ss += d * d;
  }
  atomicAdd(&colsq[col], ss);
}

// ---------------- D col-normalize + transpose -> bf16 DnT[N][K] ----------------
__global__ __launch_bounds__(256) void dnt_kernel(const float* __restrict__ D,
                                                  const float* __restrict__ colsq,
                                                  u16* __restrict__ dnt) {
  __shared__ float tile[64][65];
  const int c0 = blockIdx.x * 64, r0 = blockIdx.y * 64;
  const int t = threadIdx.x;
  const int tr = t >> 4;          // 0..15
  const int tc = (t & 15) * 4;    // 0,4,..,60
#pragma unroll
  for (int i = 0; i < 4; i++) {
    int row = i * 16 + tr;
    float4 v = *(const float4*)(D + (size_t)(r0 + row) * N_DIM + c0 + tc);
    tile[row][tc + 0] = v.x; tile[row][tc + 1] = v.y;
    tile[row][tc + 2] = v.z; tile[row][tc + 3] = v.w;
  }
  __syncthreads();
#pragma unroll
  for (int i = 0; i < 4; i++) {
    int nl = i * 16 + tr;
    float rn = 1.0f / fmaxf(sqrtf(colsq[c0 + nl]), 1e-8f);
    unsigned lo = (unsigned)f2bf(tile[tc + 0][nl] * rn) | ((unsigned)f2bf(tile[tc + 1][nl] * rn) << 16);
    unsigned hi = (unsigned)f2bf(tile[tc + 2][nl] * rn) | ((unsigned)f2bf(tile[tc + 3][nl] * rn) << 16);
    uint2 p; p.x = lo; p.y = hi;
    *(uint2*)(dnt + (size_t)(c0 + nl) * K_DIM + r0 + tc) = p;
  }
}

// ---------------- GEMM: sim = zn @ DnT^T, fused square-sum into s_accum ----------------
// A = zn [M][K] bf16 row-major; B = DnT [N][K] bf16 row-major (i.e. D_norm^T).
// Tile 128x128, 4 waves in 2x2, each wave 64x64 via 4x4 mfma_f32_16x16x32_bf16.
// LDS staged via global_load_lds (16B), with source pre-swizzle slot^=((row>>1)&3)
// so ds_read_b128 fragment reads are spread across bank-quads.
__global__ __launch_bounds__(256) void gemm_kernel(const u16* __restrict__ zn,
                                                   const u16* __restrict__ dnt,
                                                   float* __restrict__ s_accum) {
  __shared__ u16 ldsA[BM * BK];
  __shared__ u16 ldsB[BN * BK];
  const int t = threadIdx.x;
  const int w = t >> 6, l = t & 63;
  const int bm = blockIdx.y * BM;
  const int bn = blockIdx.x * BN;
  const int wm = (w >> 1) * 64;
  const int wn = (w & 1) * 64;
  const int lr = l & 15;   // fragment row (A) / col (B)
  const int lk = l >> 4;   // k-slot (8 elems each)

  floatx4 acc[4][4] = {};

  int rowS[2], offS[2];
#pragma unroll
  for (int i = 0; i < 2; i++) {
    int c = i * 256 + t;          // 16B chunk index in tile
    int row = c >> 2, slot = c & 3;
    int ss = slot ^ ((row >> 1) & 3);   // pre-swizzled source slot
    rowS[i] = row; offS[i] = ss * 8;
  }

  for (int kt = 0; kt < K_DIM; kt += BK) {
    __syncthreads();
#pragma unroll
    for (int i = 0; i < 2; i++) {
      const u16* ga = zn + (size_t)(bm + rowS[i]) * K_DIM + kt + offS[i];
      __builtin_amdgcn_global_load_lds((gu32*)ga, (lu32*)&ldsA[(i * 256 + w * 64) * 8], 16, 0, 0);
      const u16* gb = dnt + (size_t)(bn + rowS[i]) * K_DIM + kt + offS[i];
      __builtin_amdgcn_global_load_lds((gu32*)gb, (lu32*)&ldsB[(i * 256 + w * 64) * 8], 16, 0, 0);
    }
    __syncthreads();

    short8 af[4], bf[4];
#pragma unroll
    for (int m = 0; m < 4; m++) {
      int row = wm + m * 16 + lr;
      int ps = lk ^ ((row >> 1) & 3);
      af[m] = *(const short8*)&ldsA[row * BK + ps * 8];
    }
#pragma unroll
    for (int n = 0; n < 4; n++) {
      int row = wn + n * 16 + lr;
      int ps = lk ^ ((row >> 1) & 3);
      bf[n] = *(const short8*)&ldsB[row * BK + ps * 8];
    }
#pragma unroll
    for (int m = 0; m < 4; m++)
#pragma unroll
      for (int n = 0; n < 4; n++)
        acc[m][n] = __builtin_amdgcn_mfma_f32_16x16x32_bf16(af[m], bf[n], acc[m][n], 0, 0, 0);
  }

  // Epilogue: per-row sum of squares over this wave's 64 columns -> atomicAdd.
  // C/D layout: col = lane&15, row = (lane>>4)*4 + reg.
  const int cluster = (bn + wn) >> 8;   // 256-column clusters
#pragma unroll
  for (int m = 0; m < 4; m++) {
#pragma unroll
    for (int r = 0; r < 4; r++) {
      float v = 0.f;
#pragma unroll
      for (int n = 0; n < 4; n++) { float x = acc[m][n][r]; v += x * x; }
      v += __shfl_xor(v, 1, 64);
      v += __shfl_xor(v, 2, 64);
      v += __shfl_xor(v, 4, 64);
      v += __shfl_xor(v, 8, 64);
      if (lr == 0) {
        int grow = bm + wm + m * 16 + lk * 4 + r;
        atomicAdd(&s_accum[(size_t)grow * NCLUST + cluster], v);
      }
    }
  }
}

// ---------------- softmax over 16 clusters per row ----------------
__global__ __launch_bounds__(256) void softmax_kernel(const float* __restrict__ s_accum,
                                                      float* __restrict__ out0) {
  int r = blockIdx.x * 256 + threadIdx.x;
  const float4* sp = (const float4*)(s_accum + (size_t)r * 16);
  float v[16];
#pragma unroll
  for (int i = 0; i < 4; i++) {
    float4 a = sp[i];
    v[i * 4 + 0] = a.x; v[i * 4 + 1] = a.y; v[i * 4 + 2] = a.z; v[i * 4 + 3] = a.w;
  }
  float mx = -1e30f;
#pragma unroll
  for (int i = 0; i < 16; i++) { v[i] *= 10.0f; mx = fmaxf(mx, v[i]); }   // 1/TEMPERATURE = 10; +eta*d cancels in softmax
  float sum = 0.f;
#pragma unroll
  for (int i = 0; i < 16; i++) { v[i] = __expf(v[i] - mx); sum += v[i]; }
  float rs = 1.0f / sum;
  float4* op = (float4*)(out0 + (size_t)r * 16);
#pragma unroll
  for (int i = 0; i < 4; i++) {
    float4 a;
    a.x = v[i * 4 + 0] * rs; a.y = v[i * 4 + 1] * rs;
    a.z = v[i * 4 + 2] * rs; a.w = v[i * 4 + 3] * rs;
    op[i] = a;
  }
}

extern "C" void kernel_launch(void* const* d_in, const int* in_sizes, int n_in,
                              void* d_out, int out_size, void* d_ws, size_t ws_size,
                              hipStream_t stream) {
  const float* z = (const float*)d_in[0];
  const float* D = (const float*)d_in[1];
  float* out0 = (float*)d_out;
  float* out1 = out0 + (size_t)M_DIM * NCLUST;

  char* ws = (char*)d_ws;
  u16* zn   = (u16*)ws;                                               // 128 MB
  u16* dnt  = (u16*)(ws + (size_t)M_DIM * K_DIM * 2);                 // 32 MB
  float* colsq   = (float*)(ws + (size_t)M_DIM * K_DIM * 2 + (size_t)N_DIM * K_DIM * 2);
  float* s_accum = colsq + N_DIM;                                     // contiguous after colsq

  const int nzero = N_DIM + M_DIM * NCLUST;
  zero_kernel<<<(nzero + 255) / 256, 256, 0, stream>>>(colsq, nzero);
  znorm_copy_kernel<<<M_DIM, 256, 0, stream>>>(z, out1, zn);
  colsq_kernel<<<dim3(N_DIM / 256, N_DIM / 128), 256, 0, stream>>>(D, colsq);
  dnt_kernel<<<dim3(N_DIM / 64, N_DIM / 64), 256, 0, stream>>>(D, colsq, dnt);
  gemm_kernel<<<dim3(N_DIM / BN, M_DIM / BM), 256, 0, stream>>>(zn, dnt, s_accum);
  softmax_kernel<<<M_DIM / 256, 256, 0, stream>>>(s_accum, out0);
}